// Round 12
// baseline (4442.421 us; speedup 1.0000x reference)
//
#include <hip/hip_runtime.h>
#include <hip/hip_bf16.h>

#define T_STEPS 1024
// ws layout (float offsets)
#define OFF_AFT   0ull          // AfB bf16 [2048 sp][2048 s] (8MB)
#define OFF_GCAT  4194304ull
#define OFF_CFT   8388608ull
#define OFF_DELTA 10485760ull
#define OFF_BX    27262976ull
#define OFF_HS    44040192ull
#define OFF_HBUF  60817408ull   // u64[2][8192] self-tagged bf16 h words

typedef short short8 __attribute__((ext_vector_type(8)));
typedef float f32x4 __attribute__((ext_vector_type(4)));

__device__ __forceinline__ void build_oct_tables(int tid, int (*Is)[8], float (*Sg)[8]) {
  if (tid < 64) {
    int i = tid >> 3, j = tid & 7;
    int k = 0; float s = 0.f;
    if (i == 0)      { k = j; s = 1.f; }
    else if (j == 0) { k = i; s = 1.f; }
    else if (i == j) { k = 0; s = -1.f; }
    else {
      const int T7[7][3] = {{1,2,4},{2,3,5},{3,4,6},{4,5,7},{5,6,1},{6,7,2},{7,1,3}};
      for (int t = 0; t < 7; ++t) {
        int a = T7[t][0], b = T7[t][1], c = T7[t][2];
        const int P[3][3] = {{a,b,c},{b,c,a},{c,a,b}};
        for (int r = 0; r < 3; ++r) {
          if (i == P[r][0] && j == P[r][1]) { k = P[r][2]; s = 1.f; }
          if (i == P[r][1] && j == P[r][0]) { k = P[r][2]; s = -1.f; }
        }
      }
    }
    Is[j][k] = i; Sg[j][k] = s;
  }
  __syncthreads();
}

__device__ __forceinline__ unsigned short bf16r(float x) {
  unsigned u = __float_as_uint(x);
  return (unsigned short)((u + 0x7FFFu + ((u >> 16) & 1u)) >> 16);
}

// AfB[sp][s] bf16: Af[k8*256+o][j8*256+n] = Sg[j8][k8]*WA[Is[j8][k8]][o][n]
__global__ __launch_bounds__(256) void fold_Ab(const float* __restrict__ WA, unsigned short* __restrict__ AfB) {
  __shared__ int Is[8][8]; __shared__ float Sg[8][8];
  build_oct_tables(threadIdx.x, Is, Sg);
  int g8 = blockIdx.x * 256 + threadIdx.x;   // 0..524287 (2048 sp x 256 groups of 8 s)
  int sp = g8 >> 8;
  int s0 = (g8 & 255) * 8;
  int k8 = sp >> 8, o = sp & 255;
  int j8 = s0 >> 8, n = s0 & 255;
  int i = Is[j8][k8]; float sg = Sg[j8][k8];
  const float* src = WA + (size_t)i * 65536 + (size_t)o * 256 + n;
  float4 f0 = *(const float4*)(src);
  float4 f1 = *(const float4*)(src + 4);
  unsigned short v[8];
  v[0] = bf16r(sg * f0.x); v[1] = bf16r(sg * f0.y); v[2] = bf16r(sg * f0.z); v[3] = bf16r(sg * f0.w);
  v[4] = bf16r(sg * f1.x); v[5] = bf16r(sg * f1.y); v[6] = bf16r(sg * f1.z); v[7] = bf16r(sg * f1.w);
  *(short8*)(AfB + (size_t)g8 * 8) = *(short8*)v;
}

// Gcat[d][0..2047] = Wdelta[s][d],  Gcat[d][2048+sp] = Bf[sp][d]
__global__ __launch_bounds__(256) void fold_GC(const float* __restrict__ Wd, const float* __restrict__ WB,
                                               float* __restrict__ Gcat) {
  __shared__ int Is[8][8]; __shared__ float Sg[8][8];
  build_oct_tables(threadIdx.x, Is, Sg);
  int g4 = blockIdx.x * 256 + threadIdx.x;
  int col = (g4 & 1023) * 4;
  int d = g4 >> 10;
  float4 v;
  if (col < 2048) {
    v.x = Wd[(size_t)(col + 0) * 1024 + d];
    v.y = Wd[(size_t)(col + 1) * 1024 + d];
    v.z = Wd[(size_t)(col + 2) * 1024 + d];
    v.w = Wd[(size_t)(col + 3) * 1024 + d];
  } else {
    int sp = col - 2048;
    int k = sp >> 8;
    int j = d >> 7, n = d & 127;
    int i = Is[j][k]; float sg = Sg[j][k];
    const float* wb = WB + (size_t)i * 32768 + n;
    v.x = sg * wb[(size_t)((sp + 0) & 255) * 128];
    v.y = sg * wb[(size_t)((sp + 1) & 255) * 128];
    v.z = sg * wb[(size_t)((sp + 2) & 255) * 128];
    v.w = sg * wb[(size_t)((sp + 3) & 255) * 128];
  }
  *(float4*)(Gcat + (size_t)g4 * 4) = v;
}

// CfT[s][d] = Cf[d][s]
__global__ __launch_bounds__(256) void fold_C(const float* __restrict__ WC, float* __restrict__ CfT) {
  __shared__ int Is[8][8]; __shared__ float Sg[8][8];
  build_oct_tables(threadIdx.x, Is, Sg);
  int g4 = blockIdx.x * 256 + threadIdx.x;
  int d0 = (g4 & 255) * 4;
  int s  = g4 >> 8;
  int j = s >> 8, n = s & 255;
  int k = d0 >> 7;
  int i = Is[j][k]; float sg = Sg[j][k];
  const float* wc = WC + (size_t)i * 32768 + n;
  float4 v;
  v.x = sg * wc[(size_t)((d0 + 0) & 127) * 256];
  v.y = sg * wc[(size_t)((d0 + 1) & 127) * 256];
  v.z = sg * wc[(size_t)((d0 + 2) & 127) * 256];
  v.w = sg * wc[(size_t)((d0 + 3) & 127) * 256];
  *(float4*)(CfT + (size_t)g4 * 4) = v;
}

// hx word layout: idx = chunk*64 + pair*8 + b ; word = {pk(hi32) | tag(lo32)}
__global__ __launch_bounds__(256) void init_h(const float* __restrict__ h_prev, unsigned long long* __restrict__ hx) {
  int gid = blockIdx.x * 256 + threadIdx.x;  // 0..16383
  if (gid < 8192) {
    int c = gid >> 6, within = gid & 63;
    int pr = within >> 3, b = within & 7;
    int s = c * 16 + pr * 2;
    unsigned pk = (unsigned)bf16r(h_prev[(size_t)b * 2048 + s])
                | ((unsigned)bf16r(h_prev[(size_t)b * 2048 + s + 1]) << 16);
    hx[gid] = ((unsigned long long)pk << 32) | 0ull;        // tag 0
  } else {
    hx[gid] = 0x00000000FFFFFFFFull;                        // buf1 sentinel tag
  }
}

// Split-precision MFMA GEMM: C = X[8192x1024] * Gcat[1024x4096]
// cols<2048 -> sigmoid(+bias) -> delta[t][b][s]; else Bx[t][b][s]
__global__ __launch_bounds__(256) void gemm_dbx(const float* __restrict__ X, const float* __restrict__ G,
                                                const float* __restrict__ bias,
                                                float* __restrict__ dlt, float* __restrict__ Bx) {
  __shared__ unsigned short Ah[128 * 40], Al[128 * 40];   // [m][k] pitch 40
  __shared__ unsigned short Bh[128 * 40], Bl[128 * 40];   // [n][k] pitch 40
  const int bn = blockIdx.x, bm = blockIdx.y;
  const int tid = threadIdx.x;
  const int lane = tid & 63;
  const int w = tid >> 6;              // wave 0..3
  const int wr = w >> 1, wc = w & 1;   // 2x2 wave grid, 64x64 per wave
  const int lr = lane & 15, lk = lane >> 4;

  f32x4 acc[4][4];
  #pragma unroll
  for (int a = 0; a < 4; ++a)
    #pragma unroll
    for (int b = 0; b < 4; ++b) acc[a][b] = (f32x4){0.f, 0.f, 0.f, 0.f};

  for (int kt = 0; kt < 1024; kt += 32) {
    {
      int row = tid >> 1, kh = tid & 1;
      const float* ar = X + (size_t)(bm * 128 + row) * 1024 + kt + kh * 16;
      float vv[16];
      #pragma unroll
      for (int q = 0; q < 4; ++q) {
        float4 f = *(const float4*)(ar + q * 4);
        vv[q * 4 + 0] = f.x; vv[q * 4 + 1] = f.y; vv[q * 4 + 2] = f.z; vv[q * 4 + 3] = f.w;
      }
      unsigned* ah32 = (unsigned*)Ah + row * 20 + kh * 8;
      unsigned* al32 = (unsigned*)Al + row * 20 + kh * 8;
      #pragma unroll
      for (int j = 0; j < 8; ++j) {
        unsigned short h0 = bf16r(vv[2 * j]), h1 = bf16r(vv[2 * j + 1]);
        float r0 = vv[2 * j]     - __uint_as_float((unsigned)h0 << 16);
        float r1 = vv[2 * j + 1] - __uint_as_float((unsigned)h1 << 16);
        ah32[j] = (unsigned)h0 | ((unsigned)h1 << 16);
        al32[j] = (unsigned)bf16r(r0) | ((unsigned)bf16r(r1) << 16);
      }
    }
    {
      int kr = tid >> 3, cg = tid & 7;
      const float* br = G + (size_t)(kt + kr) * 4096 + bn * 128 + cg * 16;
      #pragma unroll
      for (int q = 0; q < 4; ++q) {
        float4 f = *(const float4*)(br + q * 4);
        float vv[4] = {f.x, f.y, f.z, f.w};
        #pragma unroll
        for (int e = 0; e < 4; ++e) {
          int n = cg * 16 + q * 4 + e;
          unsigned short h = bf16r(vv[e]);
          float r = vv[e] - __uint_as_float((unsigned)h << 16);
          Bh[n * 40 + kr] = h;
          Bl[n * 40 + kr] = bf16r(r);
        }
      }
    }
    __syncthreads();
    short8 ah[4], al[4], bh[4], bl[4];
    #pragma unroll
    for (int f = 0; f < 4; ++f) {
      int ma = (wr * 64 + f * 16 + lr) * 40 + lk * 8;
      int nb = (wc * 64 + f * 16 + lr) * 40 + lk * 8;
      ah[f] = *(const short8*)(Ah + ma);
      al[f] = *(const short8*)(Al + ma);
      bh[f] = *(const short8*)(Bh + nb);
      bl[f] = *(const short8*)(Bl + nb);
    }
    #pragma unroll
    for (int fm = 0; fm < 4; ++fm)
      #pragma unroll
      for (int fn = 0; fn < 4; ++fn) {
        acc[fm][fn] = __builtin_amdgcn_mfma_f32_16x16x32_bf16(ah[fm], bh[fn], acc[fm][fn], 0, 0, 0);
        acc[fm][fn] = __builtin_amdgcn_mfma_f32_16x16x32_bf16(ah[fm], bl[fn], acc[fm][fn], 0, 0, 0);
        acc[fm][fn] = __builtin_amdgcn_mfma_f32_16x16x32_bf16(al[fm], bh[fn], acc[fm][fn], 0, 0, 0);
      }
    __syncthreads();
  }
  const bool isDelta = (bn < 16);
  #pragma unroll
  for (int fm = 0; fm < 4; ++fm) {
    #pragma unroll
    for (int rr = 0; rr < 4; ++rr) {
      int r = bm * 128 + wr * 64 + fm * 16 + lk * 4 + rr;
      int t = r & 1023, b = r >> 10;
      size_t base = ((size_t)t * 8 + b) * 2048;
      #pragma unroll
      for (int fn = 0; fn < 4; ++fn) {
        int n = bn * 128 + wc * 64 + fn * 16 + lr;
        float v = acc[fm][fn][rr];
        if (isDelta) {
          v += bias[n];
          v = 1.0f / (1.0f + expf(-v));
          dlt[base + n] = v;
        } else {
          Bx[base + (n - 2048)] = v;
        }
      }
    }
  }
}

// bf16 MFMA GEMM: y[b][t][d] = sum_s hs[t*8+b][s] * CfT[s][d]
__global__ __launch_bounds__(256) void gemm_y(const float* __restrict__ HS, const float* __restrict__ CfT,
                                              float* __restrict__ out) {
  __shared__ unsigned short As[128 * 40];   // [m][k] pitch 40
  __shared__ unsigned short Bs[128 * 40];   // [n][k] pitch 40
  const int bn = blockIdx.x, bm = blockIdx.y;
  const int tid = threadIdx.x;
  const int lane = tid & 63;
  const int w = tid >> 6;
  const int wr = w >> 1, wc = w & 1;
  const int lr = lane & 15, lk = lane >> 4;

  f32x4 acc[4][4];
  #pragma unroll
  for (int a = 0; a < 4; ++a)
    #pragma unroll
    for (int b = 0; b < 4; ++b) acc[a][b] = (f32x4){0.f, 0.f, 0.f, 0.f};

  for (int kt = 0; kt < 2048; kt += 32) {
    {
      int row = tid >> 1, kh = tid & 1;
      int rg = bm * 128 + row;
      const float* ar = HS + (size_t)((rg & 1023) * 8 + (rg >> 10)) * 2048 + kt + kh * 16;
      float vv[16];
      #pragma unroll
      for (int q = 0; q < 4; ++q) {
        float4 f = *(const float4*)(ar + q * 4);
        vv[q * 4 + 0] = f.x; vv[q * 4 + 1] = f.y; vv[q * 4 + 2] = f.z; vv[q * 4 + 3] = f.w;
      }
      unsigned* a32 = (unsigned*)As + row * 20 + kh * 8;
      #pragma unroll
      for (int j = 0; j < 8; ++j)
        a32[j] = (unsigned)bf16r(vv[2 * j]) | ((unsigned)bf16r(vv[2 * j + 1]) << 16);
    }
    {
      int kr = tid >> 3, cg = tid & 7;
      const float* br = CfT + (size_t)(kt + kr) * 1024 + bn * 128 + cg * 16;
      #pragma unroll
      for (int q = 0; q < 4; ++q) {
        float4 f = *(const float4*)(br + q * 4);
        float vv[4] = {f.x, f.y, f.z, f.w};
        #pragma unroll
        for (int e = 0; e < 4; ++e)
          Bs[(cg * 16 + q * 4 + e) * 40 + kr] = bf16r(vv[e]);
      }
    }
    __syncthreads();
    short8 aF[4], bF[4];
    #pragma unroll
    for (int f = 0; f < 4; ++f) {
      aF[f] = *(const short8*)(As + (wr * 64 + f * 16 + lr) * 40 + lk * 8);
      bF[f] = *(const short8*)(Bs + (wc * 64 + f * 16 + lr) * 40 + lk * 8);
    }
    #pragma unroll
    for (int fm = 0; fm < 4; ++fm)
      #pragma unroll
      for (int fn = 0; fn < 4; ++fn)
        acc[fm][fn] = __builtin_amdgcn_mfma_f32_16x16x32_bf16(aF[fm], bF[fn], acc[fm][fn], 0, 0, 0);
    __syncthreads();
  }
  #pragma unroll
  for (int fm = 0; fm < 4; ++fm)
    #pragma unroll
    for (int rr = 0; rr < 4; ++rr) {
      size_t rg = bm * 128 + wr * 64 + fm * 16 + lk * 4 + rr;
      #pragma unroll
      for (int fn = 0; fn < 4; ++fn) {
        int n = bn * 128 + wc * 64 + fn * 16 + lr;
        out[rg * 1024 + n] = acc[fm][fn][rr];
      }
    }
}

// Persistent scan (r11 + barrier-free split-phase sync):
// 128 WGs x 512, WG owns 16 sp rows. Exchange: self-tagged u64 {bf16 pair | tag32},
// system-scope relaxed, fire-and-forget publish, dedup poll + shuffle-gather B-frags.
// NO __syncthreads in the step loop: waves write dbuf'd red partials, bump an LDS
// arrival counter; wave0 spins on cnt==8, reduces, publishes. Consumer waves fall
// straight through to the next step's poll (own-WG publish only gates one wave).
__global__ __launch_bounds__(512) void scan_kernel(const unsigned short* __restrict__ AfB,
                                                   const float* __restrict__ dlt,
                                                   const float* __restrict__ Bx, float* __restrict__ hs,
                                                   unsigned long long* __restrict__ hx,
                                                   const float* __restrict__ h_prev, float* __restrict__ hlast) {
  __shared__ float red[2][8 * 144];        // [parity][wave][m(16) pitch 9]
  __shared__ int cnt[2];                   // arrival counters, dbuf'd by parity
  const int wg = blockIdx.x;               // 0..127
  const int tid = threadIdx.x;
  const int lane = tid & 63;
  const int w = tid >> 6;                  // wave 0..7 (K-slice of 256)
  const int row = lane & 15;               // A m-row / D n-col
  const int g4 = lane >> 4;                // k-group 0..3
  const int nb = lane & 7;                 // batch (cols 8..15 duplicate)

  // A-frags: afr[q] = AfB[wg*16+row][w*256 + q*32 + g4*8 .. +7]
  short8 afr[8];
  {
    const unsigned short* ab = AfB + (size_t)(wg * 16 + row) * 2048 + w * 256 + g4 * 8;
    #pragma unroll
    for (int q = 0; q < 8; ++q)
      afr[q] = *(const short8*)(ab + q * 32);
  }
  // shuffle-gather constants: word(q,u) held by lane S(u), register p=(g4>>1)+2q
  const int S0 = (g4 & 1) * 32 + nb;       // + u*8

  // producer lanes (wave 0): ub = batch, usp = sp pair base
  const int ub = tid >> 3, usp = (tid & 7) * 2;
  const int pword = wg * 64 + (tid & 7) * 8 + ub;
  float hr0 = 0.f, hr1 = 0.f;
  if (tid < 64) {
    hr0 = h_prev[(size_t)ub * 2048 + wg * 16 + usp];
    hr1 = h_prev[(size_t)ub * 2048 + wg * 16 + usp + 1];
  }
  if (tid == 0) { cnt[0] = 0; cnt[1] = 0; }
  __syncthreads();

  #pragma unroll 1
  for (int t = 0; t < T_STEPS; ++t) {
    float2 dv = make_float2(0.f, 0.f), bxv = make_float2(0.f, 0.f);
    if (tid < 64) {
      size_t off = ((size_t)t * 8 + ub) * 2048 + wg * 16 + usp;
      dv  = *(const float2*)(dlt + off);
      bxv = *(const float2*)(Bx + off);
    }
    const unsigned want = (unsigned)t;
    const unsigned long long* bq = hx + (size_t)(t & 1) * 8192 + (size_t)w * 1024 + lane;
    unsigned long long wv[16];
    #pragma unroll
    for (int p = 0; p < 16; ++p)
      wv[p] = __hip_atomic_load(bq + p * 64, __ATOMIC_RELAXED, __HIP_MEMORY_SCOPE_SYSTEM);
    int fails = 0;
    for (;;) {
      bool stale = false;
      #pragma unroll
      for (int p = 0; p < 16; ++p) stale |= ((unsigned)wv[p] != want);
      if (!__any(stale)) break;
      if (++fails > 4) __builtin_amdgcn_s_sleep(1);
      #pragma unroll
      for (int p = 0; p < 16; ++p)
        if ((unsigned)wv[p] != want)
          wv[p] = __hip_atomic_load(bq + p * 64, __ATOMIC_RELAXED, __HIP_MEMORY_SCOPE_SYSTEM);
    }
    unsigned hi[16];
    #pragma unroll
    for (int p = 0; p < 16; ++p) hi[p] = (unsigned)(wv[p] >> 32);

    f32x4 acc = {0.f, 0.f, 0.f, 0.f};
    #pragma unroll
    for (int q = 0; q < 8; ++q) {
      union { unsigned d[4]; short8 v; } bb;
      #pragma unroll
      for (int u = 0; u < 4; ++u) {
        int S = S0 + u * 8;
        unsigned c0 = __shfl(hi[2 * q],     S, 64);
        unsigned c1 = __shfl(hi[2 * q + 1], S, 64);
        bb.d[u] = (g4 & 2) ? c1 : c0;
      }
      acc = __builtin_amdgcn_mfma_f32_16x16x32_bf16(afr[q], bb.v, acc, 0, 0, 0);
    }
    // partial D -> dbuf'd red; element (m = g4*4+r, n = row), valid n<8
    float* rb = &red[t & 1][0];
    if (row < 8) {
      #pragma unroll
      for (int r = 0; r < 4; ++r)
        rb[w * 144 + (g4 * 4 + r) * 9 + row] = acc[r];
    }
    asm volatile("s_waitcnt lgkmcnt(0)" ::: "memory");  // red writes drained before arrival
    if (lane == 0) atomicAdd(&cnt[t & 1], 1);
    if (w == 0) {
      // wave0: wait for all 8 waves' partials, then reduce + publish
      volatile int* c = &cnt[t & 1];
      while (*c < 8) { }
      float o0 = 0.f, o1 = 0.f;
      #pragma unroll
      for (int ww = 0; ww < 8; ++ww) {
        o0 += rb[ww * 144 + usp * 9 + ub];
        o1 += rb[ww * 144 + (usp + 1) * 9 + ub];
      }
      float h0 = fmaf(dv.x, o0 + bxv.x - hr0, hr0);
      float h1 = fmaf(dv.y, o1 + bxv.y - hr1, hr1);
      hr0 = h0; hr1 = h1;
      unsigned pk = (unsigned)bf16r(h0) | ((unsigned)bf16r(h1) << 16);
      unsigned long long wval = ((unsigned long long)pk << 32) | (unsigned long long)(unsigned)(t + 1);
      __hip_atomic_store(hx + (size_t)((t + 1) & 1) * 8192 + pword, wval,
                         __ATOMIC_RELAXED, __HIP_MEMORY_SCOPE_SYSTEM);   // publish first
      if (lane == 0) *c = 0;   // reset for step t+2 (safe: t+2 increments gated on own t+1 publish)
      size_t off = ((size_t)t * 8 + ub) * 2048 + wg * 16 + usp;
      *(float2*)(hs + off) = make_float2(h0, h1);
      if (t == T_STEPS - 1)
        *(float2*)(hlast + (size_t)ub * 2048 + wg * 16 + usp) = make_float2(h0, h1);
    }
    // no barrier: consumer waves proceed directly to next step's poll
  }
}

extern "C" void kernel_launch(void* const* d_in, const int* in_sizes, int n_in,
                              void* d_out, int out_size, void* d_ws, size_t ws_size,
                              hipStream_t stream) {
  const float* x      = (const float*)d_in[0];
  const float* h_prev = (const float*)d_in[1];
  const float* WA     = (const float*)d_in[2];
  const float* WB     = (const float*)d_in[3];
  const float* WC     = (const float*)d_in[4];
  const float* Wd     = (const float*)d_in[5];
  const float* bias   = (const float*)d_in[6];
  float* out = (float*)d_out;
  float* w = (float*)d_ws;
  unsigned short* AfB = (unsigned short*)(w + OFF_AFT);
  float* Gcat = w + OFF_GCAT;
  float* CfT  = w + OFF_CFT;
  float* dlt  = w + OFF_DELTA;
  float* Bx   = w + OFF_BX;
  float* hs   = w + OFF_HS;
  unsigned long long* hx = (unsigned long long*)(w + OFF_HBUF);

  fold_Ab<<<2048, 256, 0, stream>>>(WA, AfB);
  fold_GC<<<4096, 256, 0, stream>>>(Wd, WB, Gcat);
  fold_C <<<2048, 256, 0, stream>>>(WC, CfT);
  init_h <<<64,   256, 0, stream>>>(h_prev, hx);
  gemm_dbx<<<dim3(32, 64), 256, 0, stream>>>(x, Gcat, bias, dlt, Bx);
  scan_kernel<<<128, 512, 0, stream>>>(AfB, dlt, Bx, hs, hx, h_prev, out + 8388608);
  gemm_y<<<dim3(8, 64), 256, 0, stream>>>(hs, CfT, out);
}

// Round 13
// 3703.839 us; speedup vs baseline: 1.1994x; 1.1994x over previous
//
#include <hip/hip_runtime.h>
#include <hip/hip_bf16.h>

#define T_STEPS 1024
// ws layout (float offsets)
#define OFF_AFT   0ull          // AfB bf16 [2048 sp][2048 s] (8MB)
#define OFF_GCAT  4194304ull
#define OFF_CFT   8388608ull
#define OFF_DELTA 10485760ull
#define OFF_BX    27262976ull
#define OFF_HS    44040192ull
#define OFF_HBUF  60817408ull   // u64[2][8192] self-tagged bf16 h words
#define OFF_CNT   60850176ull   // int[16] per-t-chunk completion counters

typedef short short8 __attribute__((ext_vector_type(8)));
typedef float f32x4 __attribute__((ext_vector_type(4)));

__device__ __forceinline__ void build_oct_tables(int tid, int (*Is)[8], float (*Sg)[8]) {
  if (tid < 64) {
    int i = tid >> 3, j = tid & 7;
    int k = 0; float s = 0.f;
    if (i == 0)      { k = j; s = 1.f; }
    else if (j == 0) { k = i; s = 1.f; }
    else if (i == j) { k = 0; s = -1.f; }
    else {
      const int T7[7][3] = {{1,2,4},{2,3,5},{3,4,6},{4,5,7},{5,6,1},{6,7,2},{7,1,3}};
      for (int t = 0; t < 7; ++t) {
        int a = T7[t][0], b = T7[t][1], c = T7[t][2];
        const int P[3][3] = {{a,b,c},{b,c,a},{c,a,b}};
        for (int r = 0; r < 3; ++r) {
          if (i == P[r][0] && j == P[r][1]) { k = P[r][2]; s = 1.f; }
          if (i == P[r][1] && j == P[r][0]) { k = P[r][2]; s = -1.f; }
        }
      }
    }
    Is[j][k] = i; Sg[j][k] = s;
  }
  __syncthreads();
}

__device__ __forceinline__ unsigned short bf16r(float x) {
  unsigned u = __float_as_uint(x);
  return (unsigned short)((u + 0x7FFFu + ((u >> 16) & 1u)) >> 16);
}

// AfB[sp][s] bf16
__global__ __launch_bounds__(256) void fold_Ab(const float* __restrict__ WA, unsigned short* __restrict__ AfB) {
  __shared__ int Is[8][8]; __shared__ float Sg[8][8];
  build_oct_tables(threadIdx.x, Is, Sg);
  int g8 = blockIdx.x * 256 + threadIdx.x;
  int sp = g8 >> 8;
  int s0 = (g8 & 255) * 8;
  int k8 = sp >> 8, o = sp & 255;
  int j8 = s0 >> 8, n = s0 & 255;
  int i = Is[j8][k8]; float sg = Sg[j8][k8];
  const float* src = WA + (size_t)i * 65536 + (size_t)o * 256 + n;
  float4 f0 = *(const float4*)(src);
  float4 f1 = *(const float4*)(src + 4);
  unsigned short v[8];
  v[0] = bf16r(sg * f0.x); v[1] = bf16r(sg * f0.y); v[2] = bf16r(sg * f0.z); v[3] = bf16r(sg * f0.w);
  v[4] = bf16r(sg * f1.x); v[5] = bf16r(sg * f1.y); v[6] = bf16r(sg * f1.z); v[7] = bf16r(sg * f1.w);
  *(short8*)(AfB + (size_t)g8 * 8) = *(short8*)v;
}

// Gcat[d][0..2047] = Wdelta[s][d],  Gcat[d][2048+sp] = Bf[sp][d]
__global__ __launch_bounds__(256) void fold_GC(const float* __restrict__ Wd, const float* __restrict__ WB,
                                               float* __restrict__ Gcat) {
  __shared__ int Is[8][8]; __shared__ float Sg[8][8];
  build_oct_tables(threadIdx.x, Is, Sg);
  int g4 = blockIdx.x * 256 + threadIdx.x;
  int col = (g4 & 1023) * 4;
  int d = g4 >> 10;
  float4 v;
  if (col < 2048) {
    v.x = Wd[(size_t)(col + 0) * 1024 + d];
    v.y = Wd[(size_t)(col + 1) * 1024 + d];
    v.z = Wd[(size_t)(col + 2) * 1024 + d];
    v.w = Wd[(size_t)(col + 3) * 1024 + d];
  } else {
    int sp = col - 2048;
    int k = sp >> 8;
    int j = d >> 7, n = d & 127;
    int i = Is[j][k]; float sg = Sg[j][k];
    const float* wb = WB + (size_t)i * 32768 + n;
    v.x = sg * wb[(size_t)((sp + 0) & 255) * 128];
    v.y = sg * wb[(size_t)((sp + 1) & 255) * 128];
    v.z = sg * wb[(size_t)((sp + 2) & 255) * 128];
    v.w = sg * wb[(size_t)((sp + 3) & 255) * 128];
  }
  *(float4*)(Gcat + (size_t)g4 * 4) = v;
}

// CfT[s][d] = Cf[d][s]
__global__ __launch_bounds__(256) void fold_C(const float* __restrict__ WC, float* __restrict__ CfT) {
  __shared__ int Is[8][8]; __shared__ float Sg[8][8];
  build_oct_tables(threadIdx.x, Is, Sg);
  int g4 = blockIdx.x * 256 + threadIdx.x;
  int d0 = (g4 & 255) * 4;
  int s  = g4 >> 8;
  int j = s >> 8, n = s & 255;
  int k = d0 >> 7;
  int i = Is[j][k]; float sg = Sg[j][k];
  const float* wc = WC + (size_t)i * 32768 + n;
  float4 v;
  v.x = sg * wc[(size_t)((d0 + 0) & 127) * 256];
  v.y = sg * wc[(size_t)((d0 + 1) & 127) * 256];
  v.z = sg * wc[(size_t)((d0 + 2) & 127) * 256];
  v.w = sg * wc[(size_t)((d0 + 3) & 127) * 256];
  *(float4*)(CfT + (size_t)g4 * 4) = v;
}

// hx word layout: idx = chunk*64 + pair*8 + b ; word = {pk(hi32) | tag(lo32)}
__global__ __launch_bounds__(256) void init_h(const float* __restrict__ h_prev, unsigned long long* __restrict__ hx,
                                              int* __restrict__ cnt) {
  int gid = blockIdx.x * 256 + threadIdx.x;  // 0..16383
  if (gid < 8192) {
    int c = gid >> 6, within = gid & 63;
    int pr = within >> 3, b = within & 7;
    int s = c * 16 + pr * 2;
    unsigned pk = (unsigned)bf16r(h_prev[(size_t)b * 2048 + s])
                | ((unsigned)bf16r(h_prev[(size_t)b * 2048 + s + 1]) << 16);
    hx[gid] = ((unsigned long long)pk << 32) | 0ull;        // tag 0
  } else {
    hx[gid] = 0x00000000FFFFFFFFull;                        // buf1 sentinel tag
  }
  if (gid < 16) cnt[gid] = 0;
}

// Fused persistent scan (r11 protocol) + t-chunk-ordered split-precision gemm_dbx.
// Blocks 0..127: scan (WG owns 16 sp rows). Blocks 128..2175: gemm tiles, chunk-major,
// writing dlt/Bx with SYSTEM-scope stores and bumping chunkCnt[c] on completion.
__global__ __launch_bounds__(512) void scan_dbx(const unsigned short* __restrict__ AfB,
                                                float* __restrict__ dlt, float* __restrict__ Bx,
                                                float* __restrict__ hs,
                                                unsigned long long* __restrict__ hx,
                                                const float* __restrict__ h_prev, float* __restrict__ hlast,
                                                const float* __restrict__ X, const float* __restrict__ G,
                                                const float* __restrict__ bias, int* __restrict__ chunkCnt) {
  __shared__ __attribute__((aligned(16))) unsigned short Sm[4 * 128 * 40];  // 40KB, dual-role
  const int bid = blockIdx.x;
  const int tid = threadIdx.x;
  const int lane = tid & 63;

  if (bid >= 128) {
    // ---------------- gemm_dbx role (512 threads, 2x4 wave grid, 64x32 per wave) ----------------
    const int gi = bid - 128;
    const int bn = gi & 31;
    const int bmSeq = gi >> 5;             // 0..63, chunk-major
    const int ck = bmSeq >> 3, bb = bmSeq & 7;
    const int bm = ck + 8 * bb;
    unsigned short* Ah = Sm;
    unsigned short* Al = Ah + 128 * 40;
    unsigned short* Bh = Al + 128 * 40;
    unsigned short* Bl = Bh + 128 * 40;
    const int w8 = tid >> 6;
    const int wr = w8 >> 2, wc = w8 & 3;
    const int lr = lane & 15, lk = lane >> 4;

    f32x4 acc[4][2];
    #pragma unroll
    for (int a = 0; a < 4; ++a) { acc[a][0] = (f32x4){0.f,0.f,0.f,0.f}; acc[a][1] = (f32x4){0.f,0.f,0.f,0.f}; }

    for (int kt = 0; kt < 1024; kt += 32) {
      {  // A stage: row=tid>>2, kq=tid&3 (8 k each), hi/lo split
        int row = tid >> 2, kq = tid & 3;
        const float* ar = X + (size_t)(bm * 128 + row) * 1024 + kt + kq * 8;
        float4 f0 = *(const float4*)(ar);
        float4 f1 = *(const float4*)(ar + 4);
        float vv[8] = {f0.x, f0.y, f0.z, f0.w, f1.x, f1.y, f1.z, f1.w};
        unsigned* ah32 = (unsigned*)Ah + row * 20 + kq * 4;
        unsigned* al32 = (unsigned*)Al + row * 20 + kq * 4;
        #pragma unroll
        for (int j = 0; j < 4; ++j) {
          unsigned short h0 = bf16r(vv[2 * j]), h1 = bf16r(vv[2 * j + 1]);
          float r0 = vv[2 * j]     - __uint_as_float((unsigned)h0 << 16);
          float r1 = vv[2 * j + 1] - __uint_as_float((unsigned)h1 << 16);
          ah32[j] = (unsigned)h0 | ((unsigned)h1 << 16);
          al32[j] = (unsigned)bf16r(r0) | ((unsigned)bf16r(r1) << 16);
        }
      }
      {  // B stage (transpose): kr=tid>>4, cg=tid&15 (8 cols each)
        int kr = tid >> 4, cg = tid & 15;
        const float* br = G + (size_t)(kt + kr) * 4096 + bn * 128 + cg * 8;
        float4 f0 = *(const float4*)(br);
        float4 f1 = *(const float4*)(br + 4);
        float vv[8] = {f0.x, f0.y, f0.z, f0.w, f1.x, f1.y, f1.z, f1.w};
        #pragma unroll
        for (int e = 0; e < 8; ++e) {
          int n = cg * 8 + e;
          unsigned short h = bf16r(vv[e]);
          float r = vv[e] - __uint_as_float((unsigned)h << 16);
          Bh[n * 40 + kr] = h;
          Bl[n * 40 + kr] = bf16r(r);
        }
      }
      __syncthreads();
      short8 ahf[4], alf[4], bhf[2], blf[2];
      #pragma unroll
      for (int f = 0; f < 4; ++f) {
        int ma = (wr * 64 + f * 16 + lr) * 40 + lk * 8;
        ahf[f] = *(const short8*)(Ah + ma);
        alf[f] = *(const short8*)(Al + ma);
      }
      #pragma unroll
      for (int e = 0; e < 2; ++e) {
        int nb2 = (wc * 32 + e * 16 + lr) * 40 + lk * 8;
        bhf[e] = *(const short8*)(Bh + nb2);
        blf[e] = *(const short8*)(Bl + nb2);
      }
      #pragma unroll
      for (int fm = 0; fm < 4; ++fm)
        #pragma unroll
        for (int fn = 0; fn < 2; ++fn) {
          acc[fm][fn] = __builtin_amdgcn_mfma_f32_16x16x32_bf16(ahf[fm], bhf[fn], acc[fm][fn], 0, 0, 0);
          acc[fm][fn] = __builtin_amdgcn_mfma_f32_16x16x32_bf16(ahf[fm], blf[fn], acc[fm][fn], 0, 0, 0);
          acc[fm][fn] = __builtin_amdgcn_mfma_f32_16x16x32_bf16(alf[fm], bhf[fn], acc[fm][fn], 0, 0, 0);
        }
      __syncthreads();
    }
    const bool isDelta = (bn < 16);
    #pragma unroll
    for (int fm = 0; fm < 4; ++fm) {
      #pragma unroll
      for (int rr = 0; rr < 4; ++rr) {
        int r = bm * 128 + wr * 64 + fm * 16 + lk * 4 + rr;
        int t = r & 1023, b = r >> 10;
        size_t base = ((size_t)t * 8 + b) * 2048;
        #pragma unroll
        for (int fn = 0; fn < 2; ++fn) {
          int n = bn * 128 + wc * 32 + fn * 16 + lr;
          float v = acc[fm][fn][rr];
          if (isDelta) {
            v += bias[n];
            v = 1.0f / (1.0f + expf(-v));
            __hip_atomic_store(&dlt[base + n], v, __ATOMIC_RELAXED, __HIP_MEMORY_SCOPE_SYSTEM);
          } else {
            __hip_atomic_store(&Bx[base + (n - 2048)], v, __ATOMIC_RELAXED, __HIP_MEMORY_SCOPE_SYSTEM);
          }
        }
      }
    }
    __syncthreads();  // per-wave vmcnt drained at barrier -> stores at coherence point
    if (tid == 0)
      __hip_atomic_fetch_add(&chunkCnt[ck], 1, __ATOMIC_RELAXED, __HIP_MEMORY_SCOPE_SYSTEM);
    return;
  }

  // ---------------- scan role (r11 verbatim + chunk gate + setprio) ----------------
  float* red = (float*)Sm;                 // [8 waves][m(16) pitch 9] = 4608B
  const int wg = bid;                      // 0..127
  const int w = tid >> 6;                  // wave 0..7 (K-slice of 256)
  const int row = lane & 15;               // A m-row / D n-col
  const int g4 = lane >> 4;                // k-group 0..3
  const int nb = lane & 7;                 // batch (cols 8..15 duplicate)

  short8 afr[8];
  {
    const unsigned short* ab = AfB + (size_t)(wg * 16 + row) * 2048 + w * 256 + g4 * 8;
    #pragma unroll
    for (int q = 0; q < 8; ++q)
      afr[q] = *(const short8*)(ab + q * 32);
  }
  const int S0 = (g4 & 1) * 32 + nb;       // shuffle-gather source lane base (+u*8)

  const int ub = tid >> 3, usp = (tid & 7) * 2;
  const int pword = wg * 64 + (tid & 7) * 8 + ub;
  float hr0 = 0.f, hr1 = 0.f;
  if (tid < 64) {
    hr0 = h_prev[(size_t)ub * 2048 + wg * 16 + usp];
    hr1 = h_prev[(size_t)ub * 2048 + wg * 16 + usp + 1];
  }

  #pragma unroll 1
  for (int t = 0; t < T_STEPS; ++t) {
    float2 dv = make_float2(0.f, 0.f), bxv = make_float2(0.f, 0.f);
    if (tid < 64) {
      if ((t & 127) == 0) {                // once per 128 steps: gate on producer chunk
        const int ck = t >> 7;
        while (__hip_atomic_load(&chunkCnt[ck], __ATOMIC_RELAXED, __HIP_MEMORY_SCOPE_SYSTEM) < 256)
          __builtin_amdgcn_s_sleep(16);
      }
      size_t off = ((size_t)t * 8 + ub) * 2048 + wg * 16 + usp;
      dv  = *(const float2*)(dlt + off);
      bxv = *(const float2*)(Bx + off);
    }
    const unsigned want = (unsigned)t;
    const unsigned long long* bq = hx + (size_t)(t & 1) * 8192 + (size_t)w * 1024 + lane;
    unsigned long long wv[16];
    #pragma unroll
    for (int p = 0; p < 16; ++p)
      wv[p] = __hip_atomic_load(bq + p * 64, __ATOMIC_RELAXED, __HIP_MEMORY_SCOPE_SYSTEM);
    int fails = 0;
    for (;;) {
      bool stale = false;
      #pragma unroll
      for (int p = 0; p < 16; ++p) stale |= ((unsigned)wv[p] != want);
      if (!__any(stale)) break;
      if (++fails > 4) __builtin_amdgcn_s_sleep(1);
      #pragma unroll
      for (int p = 0; p < 16; ++p)
        if ((unsigned)wv[p] != want)
          wv[p] = __hip_atomic_load(bq + p * 64, __ATOMIC_RELAXED, __HIP_MEMORY_SCOPE_SYSTEM);
    }
    unsigned hi[16];
    #pragma unroll
    for (int p = 0; p < 16; ++p) hi[p] = (unsigned)(wv[p] >> 32);

    f32x4 acc = {0.f, 0.f, 0.f, 0.f};
    #pragma unroll
    for (int q = 0; q < 8; ++q) {
      union { unsigned d[4]; short8 v; } bb;
      #pragma unroll
      for (int u = 0; u < 4; ++u) {
        int S = S0 + u * 8;
        unsigned c0 = __shfl(hi[2 * q],     S, 64);
        unsigned c1 = __shfl(hi[2 * q + 1], S, 64);
        bb.d[u] = (g4 & 2) ? c1 : c0;
      }
      acc = __builtin_amdgcn_mfma_f32_16x16x32_bf16(afr[q], bb.v, acc, 0, 0, 0);
    }
    if (row < 8) {
      #pragma unroll
      for (int r = 0; r < 4; ++r)
        red[w * 144 + (g4 * 4 + r) * 9 + row] = acc[r];
    }
    __syncthreads();
    if (tid < 64) {
      __builtin_amdgcn_s_setprio(1);
      float o0 = 0.f, o1 = 0.f;
      #pragma unroll
      for (int ww = 0; ww < 8; ++ww) {
        o0 += red[ww * 144 + usp * 9 + ub];
        o1 += red[ww * 144 + (usp + 1) * 9 + ub];
      }
      float h0 = fmaf(dv.x, o0 + bxv.x - hr0, hr0);
      float h1 = fmaf(dv.y, o1 + bxv.y - hr1, hr1);
      hr0 = h0; hr1 = h1;
      unsigned pk = (unsigned)bf16r(h0) | ((unsigned)bf16r(h1) << 16);
      unsigned long long wval = ((unsigned long long)pk << 32) | (unsigned long long)(unsigned)(t + 1);
      __hip_atomic_store(hx + (size_t)((t + 1) & 1) * 8192 + pword, wval,
                         __ATOMIC_RELAXED, __HIP_MEMORY_SCOPE_SYSTEM);   // publish first
      __builtin_amdgcn_s_setprio(0);
      size_t off = ((size_t)t * 8 + ub) * 2048 + wg * 16 + usp;
      *(float2*)(hs + off) = make_float2(h0, h1);
      if (t == T_STEPS - 1)
        *(float2*)(hlast + (size_t)ub * 2048 + wg * 16 + usp) = make_float2(h0, h1);
    }
    __syncthreads();  // red reusable next step
  }
}

// bf16 MFMA GEMM: y[b][t][d] = sum_s hs[t*8+b][s] * CfT[s][d]
__global__ __launch_bounds__(256) void gemm_y(const float* __restrict__ HS, const float* __restrict__ CfT,
                                              float* __restrict__ out) {
  __shared__ unsigned short As[128 * 40];   // [m][k] pitch 40
  __shared__ unsigned short Bs[128 * 40];   // [n][k] pitch 40
  const int bn = blockIdx.x, bm = blockIdx.y;
  const int tid = threadIdx.x;
  const int lane = tid & 63;
  const int w = tid >> 6;
  const int wr = w >> 1, wc = w & 1;
  const int lr = lane & 15, lk = lane >> 4;

  f32x4 acc[4][4];
  #pragma unroll
  for (int a = 0; a < 4; ++a)
    #pragma unroll
    for (int b = 0; b < 4; ++b) acc[a][b] = (f32x4){0.f, 0.f, 0.f, 0.f};

  for (int kt = 0; kt < 2048; kt += 32) {
    {
      int row = tid >> 1, kh = tid & 1;
      int rg = bm * 128 + row;
      const float* ar = HS + (size_t)((rg & 1023) * 8 + (rg >> 10)) * 2048 + kt + kh * 16;
      float vv[16];
      #pragma unroll
      for (int q = 0; q < 4; ++q) {
        float4 f = *(const float4*)(ar + q * 4);
        vv[q * 4 + 0] = f.x; vv[q * 4 + 1] = f.y; vv[q * 4 + 2] = f.z; vv[q * 4 + 3] = f.w;
      }
      unsigned* a32 = (unsigned*)As + row * 20 + kh * 8;
      #pragma unroll
      for (int j = 0; j < 8; ++j)
        a32[j] = (unsigned)bf16r(vv[2 * j]) | ((unsigned)bf16r(vv[2 * j + 1]) << 16);
    }
    {
      int kr = tid >> 3, cg = tid & 7;
      const float* br = CfT + (size_t)(kt + kr) * 1024 + bn * 128 + cg * 16;
      #pragma unroll
      for (int q = 0; q < 4; ++q) {
        float4 f = *(const float4*)(br + q * 4);
        float vv[4] = {f.x, f.y, f.z, f.w};
        #pragma unroll
        for (int e = 0; e < 4; ++e)
          Bs[(cg * 16 + q * 4 + e) * 40 + kr] = bf16r(vv[e]);
      }
    }
    __syncthreads();
    short8 aF[4], bF[4];
    #pragma unroll
    for (int f = 0; f < 4; ++f) {
      aF[f] = *(const short8*)(As + (wr * 64 + f * 16 + lr) * 40 + lk * 8);
      bF[f] = *(const short8*)(Bs + (wc * 64 + f * 16 + lr) * 40 + lk * 8);
    }
    #pragma unroll
    for (int fm = 0; fm < 4; ++fm)
      #pragma unroll
      for (int fn = 0; fn < 4; ++fn)
        acc[fm][fn] = __builtin_amdgcn_mfma_f32_16x16x32_bf16(aF[fm], bF[fn], acc[fm][fn], 0, 0, 0);
    __syncthreads();
  }
  #pragma unroll
  for (int fm = 0; fm < 4; ++fm)
    #pragma unroll
    for (int rr = 0; rr < 4; ++rr) {
      size_t rg = bm * 128 + wr * 64 + fm * 16 + lk * 4 + rr;
      #pragma unroll
      for (int fn = 0; fn < 4; ++fn) {
        int n = bn * 128 + wc * 64 + fn * 16 + lr;
        out[rg * 1024 + n] = acc[fm][fn][rr];
      }
    }
}

extern "C" void kernel_launch(void* const* d_in, const int* in_sizes, int n_in,
                              void* d_out, int out_size, void* d_ws, size_t ws_size,
                              hipStream_t stream) {
  const float* x      = (const float*)d_in[0];
  const float* h_prev = (const float*)d_in[1];
  const float* WA     = (const float*)d_in[2];
  const float* WB     = (const float*)d_in[3];
  const float* WC     = (const float*)d_in[4];
  const float* Wd     = (const float*)d_in[5];
  const float* bias   = (const float*)d_in[6];
  float* out = (float*)d_out;
  float* w = (float*)d_ws;
  unsigned short* AfB = (unsigned short*)(w + OFF_AFT);
  float* Gcat = w + OFF_GCAT;
  float* CfT  = w + OFF_CFT;
  float* dlt  = w + OFF_DELTA;
  float* Bx   = w + OFF_BX;
  float* hs   = w + OFF_HS;
  unsigned long long* hx = (unsigned long long*)(w + OFF_HBUF);
  int* chunkCnt = (int*)(w + OFF_CNT);

  fold_Ab<<<2048, 256, 0, stream>>>(WA, AfB);
  fold_GC<<<4096, 256, 0, stream>>>(Wd, WB, Gcat);
  fold_C <<<2048, 256, 0, stream>>>(WC, CfT);
  init_h <<<64,   256, 0, stream>>>(h_prev, hx, chunkCnt);
  scan_dbx<<<2176, 512, 0, stream>>>(AfB, dlt, Bx, hs, hx, h_prev, out + 8388608,
                                     x, Gcat, bias, chunkCnt);
  gemm_y<<<dim3(8, 64), 256, 0, stream>>>(hs, CfT, out);
}